// Round 15
// baseline (2618.344 us; speedup 1.0000x reference)
//
#include <hip/hip_runtime.h>
#include <math.h>

#define DD 512
#define SS 1024
#define BB 4
#define HH 8
#define DFF 2048
#define LL 4
#define NT 4096           // BB*SS
#define EPSF 1e-5f

// ---------------- workspace layout (float elements) ----------------
#define O_X0    ((size_t)0)            // 2,097,152  emb+pe / tmp
#define O_X1    ((size_t)2097152)      // 2,097,152  conv out / current x
#define O_HSEQ  ((size_t)4194304)      // f16 activation plane (1.05M floats) + qbias
#define O_CTX   ((size_t)6293504)      // ctx f16 plane
#define O_QKV   ((size_t)8390656)      // qkv f16 plane
#define O_BIG   ((size_t)14682112)     // 16,777,216 (gates f32 / f16 scores span all / ffh f16 / W)
#define O_BSUM  ((size_t)31459328)     // 2048

typedef unsigned int  u32;
typedef unsigned short u16;
typedef __attribute__((ext_vector_type(8))) _Float16 f16x8;
typedef __attribute__((ext_vector_type(4))) float    f32x4;

__device__ __forceinline__ float fsig(float x){
  return __builtin_amdgcn_rcpf(1.0f + __expf(-x));
}
__device__ __forceinline__ float ftanh(float x){
  return 1.0f - 2.0f*__builtin_amdgcn_rcpf(1.0f + __expf(2.0f*x));
}
union f16u { u16 u; _Float16 f; };
__device__ __forceinline__ float b2f(u16 b){ f16u t; t.u = b; return (float)t.f; }
__device__ __forceinline__ u16 f2b(_Float16 h){ f16u t; t.f = h; return t.u; }
// pack f32 -> {hi f16 | lo f16} (gates weights only)
__device__ __forceinline__ u32 pack2(float v){
  _Float16 hi = (_Float16)v;
  _Float16 lo = (_Float16)(v - (float)hi);
  return (u32)f2b(hi) | ((u32)f2b(lo) << 16);
}
// 4 f32 -> 4 f16 bits in uint2
__device__ __forceinline__ uint2 pk4h(float4 v, float s){
  uint2 o;
  o.x = (u32)f2b((_Float16)(v.x*s)) | ((u32)f2b((_Float16)(v.y*s)) << 16);
  o.y = (u32)f2b((_Float16)(v.z*s)) | ((u32)f2b((_Float16)(v.w*s)) << 16);
  return o;
}

// ---------------- embedding + sinusoidal PE ----------------
__global__ void k_embed(const int* __restrict__ src, const float* __restrict__ emb,
                        float* __restrict__ x){
  int idx = blockIdx.x*256 + threadIdx.x;
  if (idx >= NT*DD) return;
  int d = idx & (DD-1);
  int n = idx >> 9;          // b*SS + s
  int s = n & (SS-1);
  int tok = src[n];
  int i2 = d & ~1;
  float div = expf(-(float)i2 * (9.210340371976184f/512.0f));  // ln(10000)/512
  float ang = (float)s * div;
  float pe = (d & 1) ? cosf(ang) : sinf(ang);
  x[idx] = emb[(size_t)tok*DD + d]*22.62741699796952f + pe;    // sqrt(512)
}

// ---------------- depthwise conv k=3 + BN(eval) + ReLU (+ f16 copy) ----------------
__global__ void k_conv(const float* __restrict__ x, const float* __restrict__ cw,
                       const float* __restrict__ cb, const float* __restrict__ bg,
                       const float* __restrict__ bb, const float* __restrict__ bm,
                       const float* __restrict__ bv, float* __restrict__ y,
                       u16* __restrict__ yp){
  int idx = blockIdx.x*256 + threadIdx.x;
  if (idx >= NT*DD) return;
  int d = idx & (DD-1);
  int n = idx >> 9;
  int s = n & (SS-1);
  float acc = cb[d];
  if (s > 0)     acc += x[idx - DD]*cw[d*3+0];
  acc += x[idx]*cw[d*3+1];
  if (s < SS-1)  acc += x[idx + DD]*cw[d*3+2];
  float v = (acc - bm[d])*rsqrtf(bv[d]+EPSF)*bg[d] + bb[d];
  v = fmaxf(v, 0.0f);
  y[idx] = v;
  yp[idx] = f2b((_Float16)v);
}

__global__ void k_bsum(const float* a, const float* b, float* o, int n){
  int i = blockIdx.x*256 + threadIdx.x;
  if (i < n) o[i] = a[i] + b[i];
}

// gates weight split: f32 -> packed {hi|lo} u32 (2-pass path keeps LSTM input accurate)
__global__ void k_wsplit(const float* __restrict__ W, u32* __restrict__ Wp, int total){
  int i = blockIdx.x*1024 + threadIdx.x*4;
  if (i >= total) return;
  float4 v = *reinterpret_cast<const float4*>(W + i);
  uint4 o;
  o.x = pack2(v.x); o.y = pack2(v.y); o.z = pack2(v.z); o.w = pack2(v.w);
  *reinterpret_cast<uint4*>(Wp + i) = o;
}

// qkv weight split -> f16 plane (rows<512 scaled 0.125) + scaled bias. 768 blocks.
__global__ void k_wsplit_qkv(const float* __restrict__ inw, const float* __restrict__ inb,
                             u16* __restrict__ Wq, float* __restrict__ qbias){
  size_t i = (size_t)blockIdx.x*1024 + threadIdx.x*4;
  float s = (i < 262144) ? 0.125f : 1.0f;
  float4 v = *reinterpret_cast<const float4*>(inw + i);
  *reinterpret_cast<uint2*>(Wq + i) = pk4h(v, s);
  if (blockIdx.x == 0){
    for (int j = threadIdx.x; j < 1536; j += 256){
      float bv = inb[j];
      qbias[j] = (j < 512) ? bv*0.125f : bv;
    }
  }
}

// post-attention fused split -> f16 planes: out_w 262,144 | w1 1,048,576 | w2 1,048,576
__global__ void k_wsplit_post(const float* __restrict__ outw, const float* __restrict__ w1,
                              const float* __restrict__ w2,
                              u16* __restrict__ Wo, u16* __restrict__ W1p,
                              u16* __restrict__ W2p){
  size_t i = (size_t)blockIdx.x*1024 + threadIdx.x*4;
  const float* src; u16* dst; size_t off;
  if (i < 262144){ src = outw; dst = Wo; off = i; }
  else if (i < 1310720){ src = w1; dst = W1p; off = i - 262144; }
  else { src = w2; dst = W2p; off = i - 1310720; }
  float4 v = *reinterpret_cast<const float4*>(src + off);
  *reinterpret_cast<uint2*>(dst + off) = pk4h(v, 1.0f);
}

// packed-u32 unpack (gates W only)
__device__ __forceinline__ void unpk4(uint4 w, uint2& hi, uint2& lo){
  hi.x = (w.x & 0xffffu) | (w.y << 16);
  hi.y = (w.z & 0xffffu) | (w.w << 16);
  lo.x = (w.x >> 16) | (w.y & 0xffff0000u);
  lo.y = (w.z >> 16) | (w.w & 0xffff0000u);
}

#define BKP 40   // padded K stride in halves (80 B rows, 16B-aligned)

// ---------------- gates GEMM (2-pass W): C = A(f16) @ Wpacked^T + bias -> f32 ----------------
__global__ __launch_bounds__(256) void k_gemm2p(const u16* __restrict__ A,
                                                const u32* __restrict__ Wp,
                                                const float* __restrict__ bias,
                                                float* __restrict__ C,
                                                int M, int N, int K){
  __shared__ _Float16 Ah[128][BKP];
  __shared__ _Float16 Wh[128][BKP];
  __shared__ _Float16 Wl[128][BKP];
  const int tid = threadIdx.x;
  const int nbx = N >> 7;
  const int bx = blockIdx.x % nbx;
  const int by = blockIdx.x / nbx;
  const int m0 = by << 7, n0 = bx << 7;
  const int lane = tid & 63;
  const int wid  = tid >> 6;
  const int wr = wid >> 1, wc = wid & 1;
  const int fm = lane & 15, fg = lane >> 4;
  const int r0a = tid >> 2;             // A staging rows r0a + 64e
  const int k8  = (tid & 3) << 3;
  const int r0w = tid >> 3;             // W staging rows r0w + 32e
  const int k4  = (tid & 7) << 2;
  const u16* Abase = A + (size_t)(m0 + r0a)*K + k8;
  const u32* Wbase = Wp + (size_t)(n0 + r0w)*K + k4;

  f32x4 acc[4][4];
  #pragma unroll
  for (int i=0;i<4;i++)
    #pragma unroll
    for (int j=0;j<4;j++) acc[i][j] = (f32x4){0.0f,0.0f,0.0f,0.0f};

  uint4 ra[2], rw[4];
  #pragma unroll
  for (int e=0;e<2;e++) ra[e] = *reinterpret_cast<const uint4*>(Abase + (size_t)(e*64)*K);
  #pragma unroll
  for (int e=0;e<4;e++) rw[e] = *reinterpret_cast<const uint4*>(Wbase + (size_t)(e*32)*K);

  for (int k0 = 0; k0 < K; k0 += 32){
    #pragma unroll
    for (int e=0;e<2;e++)
      *reinterpret_cast<uint4*>(&Ah[r0a + e*64][k8]) = ra[e];
    #pragma unroll
    for (int e=0;e<4;e++){
      uint2 hi, lo;
      unpk4(rw[e], hi, lo);
      *reinterpret_cast<uint2*>(&Wh[r0w + e*32][k4]) = hi;
      *reinterpret_cast<uint2*>(&Wl[r0w + e*32][k4]) = lo;
    }
    __syncthreads();
    if (k0 + 32 < K){
      #pragma unroll
      for (int e=0;e<2;e++)
        ra[e] = *reinterpret_cast<const uint4*>(Abase + (size_t)(e*64)*K + k0 + 32);
      #pragma unroll
      for (int e=0;e<4;e++)
        rw[e] = *reinterpret_cast<const uint4*>(Wbase + (size_t)(e*32)*K + k0 + 32);
    }
    f16x8 a_h[4], w_h[4], w_l[4];
    #pragma unroll
    for (int i=0;i<4;i++)
      a_h[i] = *reinterpret_cast<const f16x8*>(&Ah[wr*64 + i*16 + fm][fg*8]);
    #pragma unroll
    for (int j=0;j<4;j++){
      w_h[j] = *reinterpret_cast<const f16x8*>(&Wh[wc*64 + j*16 + fm][fg*8]);
      w_l[j] = *reinterpret_cast<const f16x8*>(&Wl[wc*64 + j*16 + fm][fg*8]);
    }
    #pragma unroll
    for (int i=0;i<4;i++)
      #pragma unroll
      for (int j=0;j<4;j++){
        acc[i][j] = __builtin_amdgcn_mfma_f32_16x16x32_f16(a_h[i], w_h[j], acc[i][j], 0, 0, 0);
        acc[i][j] = __builtin_amdgcn_mfma_f32_16x16x32_f16(a_h[i], w_l[j], acc[i][j], 0, 0, 0);
      }
    __syncthreads();
  }
  #pragma unroll
  for (int i=0;i<4;i++){
    #pragma unroll
    for (int r=0;r<4;r++){
      int row = m0 + wr*64 + i*16 + fg*4 + r;
      #pragma unroll
      for (int j=0;j<4;j++){
        int col = n0 + wc*64 + j*16 + fm;
        C[(size_t)row*N + col] = acc[i][j][r] + bias[col];
      }
    }
  }
}

// ---------------- 1-pass f16 GEMM, BN=128: C = A(f16) @ W(f16)^T + bias ----------------
template<int ACT, int OHALF>
__global__ __launch_bounds__(256) void k_gemmh(const u16* __restrict__ A,
                                               const u16* __restrict__ W,
                                               const float* __restrict__ bias,
                                               void* __restrict__ Cout,
                                               int M, int N, int K){
  __shared__ _Float16 Ah[128][BKP];
  __shared__ _Float16 Wh[128][BKP];
  const int tid = threadIdx.x;
  const int nbx = N >> 7;
  const int bx = blockIdx.x % nbx;
  const int by = blockIdx.x / nbx;
  const int m0 = by << 7, n0 = bx << 7;
  const int lane = tid & 63;
  const int wid  = tid >> 6;
  const int wr = wid >> 1, wc = wid & 1;
  const int fm = lane & 15, fg = lane >> 4;
  const int r0 = tid >> 2;              // staging rows r0 + 64e
  const int k8 = (tid & 3) << 3;
  const u16* Abase = A + (size_t)(m0 + r0)*K + k8;
  const u16* Wbase = W + (size_t)(n0 + r0)*K + k8;

  f32x4 acc[4][4];
  #pragma unroll
  for (int i=0;i<4;i++)
    #pragma unroll
    for (int j=0;j<4;j++) acc[i][j] = (f32x4){0.0f,0.0f,0.0f,0.0f};

  uint4 ra[2], rw[2];
  #pragma unroll
  for (int e=0;e<2;e++){
    ra[e] = *reinterpret_cast<const uint4*>(Abase + (size_t)(e*64)*K);
    rw[e] = *reinterpret_cast<const uint4*>(Wbase + (size_t)(e*64)*K);
  }

  for (int k0 = 0; k0 < K; k0 += 32){
    #pragma unroll
    for (int e=0;e<2;e++){
      *reinterpret_cast<uint4*>(&Ah[r0 + e*64][k8]) = ra[e];
      *reinterpret_cast<uint4*>(&Wh[r0 + e*64][k8]) = rw[e];
    }
    __syncthreads();
    if (k0 + 32 < K){
      #pragma unroll
      for (int e=0;e<2;e++){
        ra[e] = *reinterpret_cast<const uint4*>(Abase + (size_t)(e*64)*K + k0 + 32);
        rw[e] = *reinterpret_cast<const uint4*>(Wbase + (size_t)(e*64)*K + k0 + 32);
      }
    }
    f16x8 a_h[4], w_h[4];
    #pragma unroll
    for (int i=0;i<4;i++)
      a_h[i] = *reinterpret_cast<const f16x8*>(&Ah[wr*64 + i*16 + fm][fg*8]);
    #pragma unroll
    for (int j=0;j<4;j++)
      w_h[j] = *reinterpret_cast<const f16x8*>(&Wh[wc*64 + j*16 + fm][fg*8]);
    #pragma unroll
    for (int i=0;i<4;i++)
      #pragma unroll
      for (int j=0;j<4;j++)
        acc[i][j] = __builtin_amdgcn_mfma_f32_16x16x32_f16(a_h[i], w_h[j], acc[i][j], 0, 0, 0);
    __syncthreads();
  }
  #pragma unroll
  for (int i=0;i<4;i++){
    #pragma unroll
    for (int r=0;r<4;r++){
      int row = m0 + wr*64 + i*16 + fg*4 + r;
      #pragma unroll
      for (int j=0;j<4;j++){
        int col = n0 + wc*64 + j*16 + fm;
        float v = acc[i][j][r] + bias[col];
        if (ACT == 1) v = 0.5f*v*(1.0f + erff(v*0.70710678118654752f));  // exact gelu
        if constexpr (OHALF) ((u16*)Cout)[(size_t)row*N + col] = f2b((_Float16)v);
        else                 ((float*)Cout)[(size_t)row*N + col] = v;
      }
    }
  }
}

// ---------------- 1-pass f16 GEMM, BN=64 (full-chip grids for N=512) ----------------
template<int ACT, int OHALF>
__global__ __launch_bounds__(256) void k_gemm64h(const u16* __restrict__ A,
                                                 const u16* __restrict__ W,
                                                 const float* __restrict__ bias,
                                                 void* __restrict__ Cout,
                                                 int M, int N, int K){
  __shared__ _Float16 Ah[128][BKP];
  __shared__ _Float16 Wh[64][BKP];
  const int tid = threadIdx.x;
  const int nbx = N >> 6;
  const int bx = blockIdx.x % nbx;
  const int by = blockIdx.x / nbx;
  const int m0 = by << 7, n0 = bx << 6;
  const int lane = tid & 63;
  const int wid  = tid >> 6;
  const int wr = wid >> 1, wc = wid & 1;   // wave tile: 64 rows x 32 cols
  const int fm = lane & 15, fg = lane >> 4;
  const int r0 = tid >> 2;              // 0..63
  const int k8 = (tid & 3) << 3;
  const u16* Abase = A + (size_t)(m0 + r0)*K + k8;
  const u16* Wbase = W + (size_t)(n0 + r0)*K + k8;

  f32x4 acc[4][2];
  #pragma unroll
  for (int i=0;i<4;i++){ acc[i][0] = (f32x4){0,0,0,0}; acc[i][1] = (f32x4){0,0,0,0}; }

  uint4 ra[2], rw0;
  #pragma unroll
  for (int e=0;e<2;e++)
    ra[e] = *reinterpret_cast<const uint4*>(Abase + (size_t)(e*64)*K);
  rw0 = *reinterpret_cast<const uint4*>(Wbase);

  for (int k0 = 0; k0 < K; k0 += 32){
    #pragma unroll
    for (int e=0;e<2;e++)
      *reinterpret_cast<uint4*>(&Ah[r0 + e*64][k8]) = ra[e];
    *reinterpret_cast<uint4*>(&Wh[r0][k8]) = rw0;
    __syncthreads();
    if (k0 + 32 < K){
      #pragma unroll
      for (int e=0;e<2;e++)
        ra[e] = *reinterpret_cast<const uint4*>(Abase + (size_t)(e*64)*K + k0 + 32);
      rw0 = *reinterpret_cast<const uint4*>(Wbase + k0 + 32);
    }
    f16x8 a_h[4], w_h[2];
    #pragma unroll
    for (int i=0;i<4;i++)
      a_h[i] = *reinterpret_cast<const f16x8*>(&Ah[wr*64 + i*16 + fm][fg*8]);
    #pragma unroll
    for (int j=0;j<2;j++)
      w_h[j] = *reinterpret_cast<const f16x8*>(&Wh[wc*32 + j*16 + fm][fg*8]);
    #pragma unroll
    for (int i=0;i<4;i++)
      #pragma unroll
      for (int j=0;j<2;j++)
        acc[i][j] = __builtin_amdgcn_mfma_f32_16x16x32_f16(a_h[i], w_h[j], acc[i][j], 0, 0, 0);
    __syncthreads();
  }
  #pragma unroll
  for (int i=0;i<4;i++){
    #pragma unroll
    for (int r=0;r<4;r++){
      int row = m0 + wr*64 + i*16 + fg*4 + r;
      #pragma unroll
      for (int j=0;j<2;j++){
        int col = n0 + wc*32 + j*16 + fm;
        float v = acc[i][j][r] + bias[col];
        if (ACT == 1) v = 0.5f*v*(1.0f + erff(v*0.70710678118654752f));
        if constexpr (OHALF) ((u16*)Cout)[(size_t)row*N + col] = f2b((_Float16)v);
        else                 ((float*)Cout)[(size_t)row*N + col] = v;
      }
    }
  }
}

// ---------------- scores: sc = Qs @ K^T, f16 x f16, 128x128 tiles, all batches ----------------
#define SPAD 72
__global__ __launch_bounds__(256) void k_scores_mfma(const u16* __restrict__ qkv,
                                                     u16* __restrict__ sc){
  __shared__ _Float16 Qh[128][SPAD];
  __shared__ _Float16 Kh[128][SPAD];
  const int tid = threadIdx.x;
  const int kt = blockIdx.x & 7;
  const int qt = (blockIdx.x >> 3) & 7;
  const int h  = (blockIdx.x >> 6) & 7;
  const int b  = (blockIdx.x >> 9) & 3;
  const int q0 = qt*128, k0 = kt*128;
  #pragma unroll
  for (int e=0;e<4;e++){
    int lin = e*256 + tid;
    int rr = lin >> 3;          // 0..127
    int c8 = (lin & 7) << 3;    // 0..56
    *reinterpret_cast<uint4*>(&Qh[rr][c8]) =
      *reinterpret_cast<const uint4*>(qkv + (size_t)(b*SS + q0+rr)*1536 + h*64 + c8);
    *reinterpret_cast<uint4*>(&Kh[rr][c8]) =
      *reinterpret_cast<const uint4*>(qkv + (size_t)(b*SS + k0+rr)*1536 + DD + h*64 + c8);
  }
  __syncthreads();
  const int lane = tid & 63, wid = tid >> 6;
  const int wr = wid >> 1, wc = wid & 1;
  const int fm = lane & 15, fg = lane >> 4;
  f32x4 acc[4][4];
  #pragma unroll
  for (int i=0;i<4;i++)
    #pragma unroll
    for (int j=0;j<4;j++) acc[i][j] = (f32x4){0.0f,0.0f,0.0f,0.0f};
  #pragma unroll
  for (int ks=0; ks<2; ks++){
    f16x8 ah[4], bh[4];
    #pragma unroll
    for (int i=0;i<4;i++)
      ah[i] = *reinterpret_cast<const f16x8*>(&Qh[wr*64 + i*16 + fm][ks*32 + fg*8]);
    #pragma unroll
    for (int j=0;j<4;j++)
      bh[j] = *reinterpret_cast<const f16x8*>(&Kh[wc*64 + j*16 + fm][ks*32 + fg*8]);
    #pragma unroll
    for (int i=0;i<4;i++)
      #pragma unroll
      for (int j=0;j<4;j++)
        acc[i][j] = __builtin_amdgcn_mfma_f32_16x16x32_f16(ah[i], bh[j], acc[i][j], 0, 0, 0);
  }
  u16* out = sc + (size_t)(b*HH + h)*SS*SS;
  #pragma unroll
  for (int i=0;i<4;i++){
    #pragma unroll
    for (int r=0;r<4;r++){
      int row = q0 + wr*64 + i*16 + fg*4 + r;
      #pragma unroll
      for (int j=0;j<4;j++){
        int col = k0 + wc*64 + j*16 + fm;
        out[(size_t)row*SS + col] = f2b((_Float16)acc[i][j][r]);
      }
    }
  }
}

// ---------------- PV: ctx = P @ V, f16 x f16, 64q x 64d tiles, all batches ----------------
__global__ __launch_bounds__(256) void k_pv_mfma(const u16* __restrict__ sc,
                                                 const u16* __restrict__ qkv,
                                                 u16* __restrict__ ctx){
  __shared__ _Float16 Ph[64][SPAD];
  __shared__ _Float16 Vh[64][SPAD];
  const int tid = threadIdx.x;
  const int qt = blockIdx.x & 15;
  const int h  = (blockIdx.x >> 4) & 7;
  const int b  = (blockIdx.x >> 7) & 3;
  const int q0 = qt*64;
  const u16* Pb = sc + (size_t)(b*HH + h)*SS*SS;
  const int lane = tid & 63, wid = tid >> 6;
  const int wr = wid >> 1, wc = wid & 1;      // wave tile: 32 rows x 32 cols
  const int fm = lane & 15, fg = lane >> 4;
  const int pr0 = tid >> 3;                   // P staging rows pr0 + 32e
  const int pc8 = (tid & 7) << 3;
  const int vd  = tid & 63;                   // V staging: dim
  const int vk0 = tid >> 6;                   // V staging: k = vk0 + 4e
  const u16* Pbase = Pb + (size_t)(q0 + pr0)*SS + pc8;
  const u16* Vbase = qkv + (size_t)(b*SS + vk0)*1536 + 1024 + h*64 + vd;
  f32x4 acc[2][2];
  #pragma unroll
  for (int i=0;i<2;i++){ acc[i][0] = (f32x4){0,0,0,0}; acc[i][1] = (f32x4){0,0,0,0}; }

  uint4 rp[2];
  u16   rv[16];
  #pragma unroll
  for (int e=0;e<2;e++) rp[e] = *reinterpret_cast<const uint4*>(Pbase + (size_t)(e*32)*SS);
  #pragma unroll
  for (int e=0;e<16;e++) rv[e] = Vbase[(size_t)(e*4)*1536];

  for (int kk0=0; kk0<SS; kk0+=64){
    #pragma unroll
    for (int e=0;e<2;e++)
      *reinterpret_cast<uint4*>(&Ph[pr0 + e*32][pc8]) = rp[e];
    #pragma unroll
    for (int e=0;e<16;e++){
      f16u t; t.u = rv[e];
      Vh[vd][vk0 + e*4] = t.f;
    }
    __syncthreads();
    if (kk0 + 64 < SS){
      #pragma unroll
      for (int e=0;e<2;e++)
        rp[e] = *reinterpret_cast<const uint4*>(Pbase + (size_t)(e*32)*SS + kk0 + 64);
      #pragma unroll
      for (int e=0;e<16;e++)
        rv[e] = Vbase[(size_t)(kk0 + 64 + e*4)*1536];
    }
    #pragma unroll
    for (int ks=0; ks<2; ks++){
      f16x8 ah[2], bh[2];
      #pragma unroll
      for (int i=0;i<2;i++)
        ah[i] = *reinterpret_cast<const f16x8*>(&Ph[wr*32 + i*16 + fm][ks*32 + fg*8]);
      #pragma unroll
      for (int j=0;j<2;j++)
        bh[j] = *reinterpret_cast<const f16x8*>(&Vh[wc*32 + j*16 + fm][ks*32 + fg*8]);
      #pragma unroll
      for (int i=0;i<2;i++)
        #pragma unroll
        for (int j=0;j<2;j++)
          acc[i][j] = __builtin_amdgcn_mfma_f32_16x16x32_f16(ah[i], bh[j], acc[i][j], 0, 0, 0);
    }
    __syncthreads();
  }
  #pragma unroll
  for (int i=0;i<2;i++){
    #pragma unroll
    for (int r=0;r<4;r++){
      int row = q0 + wr*32 + i*16 + fg*4 + r;
      #pragma unroll
      for (int j=0;j<2;j++){
        int col = wc*32 + j*16 + fm;
        ctx[(size_t)(b*SS + row)*DD + h*64 + col] = f2b((_Float16)acc[i][j][r]);
      }
    }
  }
}

// ---------------- persistent LSTM: FROZEN (R9-verified) ----------------
__global__ __launch_bounds__(256) void k_lstm(const float* __restrict__ gates_in,
                                              const float* __restrict__ w_hh,
                                              unsigned long long* __restrict__ hpack){
  __shared__ float hsh[2][8][68];
  const int b = blockIdx.x >> 6;
  const int chunk = blockIdx.x & 63;
  const int d0 = chunk*8;
  const int tid = threadIdx.x;
  const int wave = tid >> 6;
  const int lane = tid & 63;
  const int diw = lane >> 5;
  const int g   = (lane >> 3) & 3;
  const int ks  = lane & 7;
  const int dim = wave*2 + diw;
  const int src0 = diw*32;
  float w[64];
  {
    const float* wrow = w_hh + (size_t)(g*DD + d0 + dim)*DD;
    #pragma unroll
    for (int j=0;j<64;j++) w[j] = wrow[j*8 + ks];
  }
  float c = 0.0f;
  const float* gbase = gates_in + (size_t)(b*SS)*(4*DD) + g*DD + d0 + dim;
  unsigned long long p0 = __hip_atomic_load(hpack + (size_t)b*DD + tid,
                                            __ATOMIC_RELAXED, __HIP_MEMORY_SCOPE_AGENT);
  unsigned long long p1 = __hip_atomic_load(hpack + (size_t)b*DD + tid + 256,
                                            __ATOMIC_RELAXED, __HIP_MEMORY_SCOPE_AGENT);
  for (int t=0; t<SS; ++t){
    float gv = 0.0f;
    if (ks == 0) gv = gbase[(size_t)t*(4*DD)];
    const unsigned long long exp_tag = (unsigned long long)t;
    unsigned long long* hp = hpack + (size_t)(t*BB + b)*DD;
    while ((p0 >> 32) != exp_tag || (p1 >> 32) != exp_tag){
      if ((p0 >> 32) != exp_tag)
        p0 = __hip_atomic_load(hp + tid,       __ATOMIC_RELAXED, __HIP_MEMORY_SCOPE_AGENT);
      if ((p1 >> 32) != exp_tag)
        p1 = __hip_atomic_load(hp + tid + 256, __ATOMIC_RELAXED, __HIP_MEMORY_SCOPE_AGENT);
    }
    float (*hs)[68] = hsh[t & 1];
    union { unsigned int u; float f; } u0, u1;
    u0.u = (unsigned int)p0;
    u1.u = (unsigned int)p1;
    hs[tid & 7][tid >> 3]        = u0.f;
    hs[tid & 7][(tid >> 3) + 32] = u1.f;
    __syncthreads();
    if (t + 1 < SS){
      unsigned long long* hq = hpack + (size_t)((t+1)*BB + b)*DD;
      p0 = __hip_atomic_load(hq + tid,       __ATOMIC_RELAXED, __HIP_MEMORY_SCOPE_AGENT);
      p1 = __hip_atomic_load(hq + tid + 256, __ATOMIC_RELAXED, __HIP_MEMORY_SCOPE_AGENT);
    }
    float a0=0.0f, a1=0.0f, a2=0.0f, a3=0.0f;
    #pragma unroll
    for (int j=0;j<64;j+=4){
      float4 hv = *reinterpret_cast<const float4*>(&hs[ks][j]);
      a0 += w[j+0]*hv.x;
      a1 += w[j+1]*hv.y;
      a2 += w[j+2]*hv.z;
      a3 += w[j+3]*hv.w;
    }
    float acc = (a0+a1)+(a2+a3);
    acc += __shfl_down(acc, 4, 8);
    acc += __shfl_down(acc, 2, 8);
    acc += __shfl_down(acc, 1, 8);
    float v = acc + gv;
    float gval = (g == 2) ? ftanh(v) : fsig(v);
    float gi = __shfl(gval, src0 + 0);
    float gf = __shfl(gval, src0 + 8);
    float gg = __shfl(gval, src0 + 16);
    float go = __shfl(gval, src0 + 24);
    c = gf*c + gi*gg;
    float h = go*ftanh(c);
    if (lane == src0){
      union { float f; unsigned int u; } hu; hu.f = h;
      unsigned long long pk = ((unsigned long long)(unsigned int)(t+1) << 32)
                            | (unsigned long long)hu.u;
      __hip_atomic_store(&hpack[(size_t)((t+1)*BB + b)*DD + d0 + dim], pk,
                         __ATOMIC_RELAXED, __HIP_MEMORY_SCOPE_AGENT);
    }
  }
}

__global__ void k_resid(float* __restrict__ x, const unsigned long long* __restrict__ hpack,
                        u16* __restrict__ xp){
  int idx = blockIdx.x*256 + threadIdx.x;
  if (idx >= NT*DD) return;
  int d = idx & (DD-1);
  int n = idx >> 9;
  int s = n & (SS-1);
  int b = n >> 10;
  union { unsigned int u; float f; } hu;
  hu.u = (unsigned int)hpack[(size_t)((s+1)*BB + b)*DD + d];
  float v = x[idx] + hu.f;
  x[idx] = v;
  xp[idx] = f2b((_Float16)v);
}

// softmax: f16 scores in, f16 P in-place + head-average to d_out. 4096 blocks.
__global__ __launch_bounds__(256) void k_softmax(u16* __restrict__ sc,
                                                 float* __restrict__ attn_out,
                                                 int l){
  __shared__ float avgw[4][SS];
  const int tid = threadIdx.x;
  const int q  = blockIdx.x & (SS-1);
  const int b  = blockIdx.x >> 10;
  const int wave = tid >> 6, lane = tid & 63;
  #pragma unroll
  for (int j=0;j<16;j++) avgw[wave][j*64 + lane] = 0.0f;
  #pragma unroll
  for (int hi=0; hi<2; hi++){
    int h = wave + hi*4;
    u16* row = sc + (size_t)(b*HH + h)*SS*SS + (size_t)q*SS;
    float v[16];
    float m = -1e30f;
    #pragma unroll
    for (int j=0;j<16;j++){ v[j] = b2f(row[j*64 + lane]); m = fmaxf(m, v[j]); }
    #pragma unroll
    for (int o=32;o>0;o>>=1) m = fmaxf(m, __shfl_xor(m, o));
    float s = 0.0f;
    #pragma unroll
    for (int j=0;j<16;j++){ v[j] = __expf(v[j] - m); s += v[j]; }
    #pragma unroll
    for (int o=32;o>0;o>>=1) s += __shfl_xor(s, o);
    float inv = __builtin_amdgcn_rcpf(s);
    #pragma unroll
    for (int j=0;j<16;j++){
      float p = v[j]*inv;
      row[j*64 + lane] = f2b((_Float16)p);
      avgw[wave][j*64 + lane] += p;
    }
  }
  __syncthreads();
  float* ao = attn_out + (size_t)((l*BB + b)*SS + q)*SS;
  for (int j=tid;j<SS;j+=256)
    ao[j] = (avgw[0][j]+avgw[1][j]+avgw[2][j]+avgw[3][j])*0.125f;
}

// ---------------- LayerNorm: out = LN(x (+ y)) * g + b  (+ optional f16 copy) ----------------
__global__ __launch_bounds__(64) void k_ln(const float* __restrict__ x,
                                           const float* __restrict__ y,
                                           const float* __restrict__ g,
                                           const float* __restrict__ bta,
                                           float* __restrict__ out,
                                           u16* __restrict__ outp){
  const int n = blockIdx.x;
  const int tid = threadIdx.x;
  float v[8];
  float s = 0.0f, sq = 0.0f;
  #pragma unroll
  for (int j=0;j<8;j++){
    int d = j*64 + tid;
    float a = x[(size_t)n*DD + d];
    if (y) a += y[(size_t)n*DD + d];
    v[j] = a; s += a; sq += a*a;
  }
  #pragma unroll
  for (int o=32;o>0;o>>=1){ s += __shfl_xor(s, o); sq += __shfl_xor(sq, o); }
  float mean = s*(1.0f/DD);
  float var = sq*(1.0f/DD) - mean*mean;
  float rstd = rsqrtf(var + EPSF);
  #pragma unroll
  for (int j=0;j<8;j++){
    int d = j*64 + tid;
    float r = (v[j]-mean)*rstd*g[d] + bta[d];
    out[(size_t)n*DD + d] = r;
    if (outp) outp[(size_t)n*DD + d] = f2b((_Float16)r);
  }
}

extern "C" void kernel_launch(void* const* d_in, const int* in_sizes, int n_in,
                              void* d_out, int out_size, void* d_ws, size_t ws_size,
                              hipStream_t stream){
  const int*   src    = (const int*)  d_in[0];
  const float* emb    = (const float*)d_in[1];
  const float* conv_w = (const float*)d_in[2];
  const float* conv_b = (const float*)d_in[3];
  const float* bn_g   = (const float*)d_in[4];
  const float* bn_b   = (const float*)d_in[5];
  const float* bn_m   = (const float*)d_in[6];
  const float* bn_v   = (const float*)d_in[7];
  const float* w_ih   = (const float*)d_in[8];
  const float* w_hh   = (const float*)d_in[9];
  const float* b_ih   = (const float*)d_in[10];
  const float* b_hh   = (const float*)d_in[11];
  const float* in_w   = (const float*)d_in[12];
  const float* in_b   = (const float*)d_in[13];
  const float* out_w  = (const float*)d_in[14];
  const float* out_b  = (const float*)d_in[15];
  const float* ln1_g  = (const float*)d_in[16];
  const float* ln1_b  = (const float*)d_in[17];
  const float* w1     = (const float*)d_in[18];
  const float* b1     = (const float*)d_in[19];
  const float* w2     = (const float*)d_in[20];
  const float* b2     = (const float*)d_in[21];
  const float* ln2_g  = (const float*)d_in[22];
  const float* ln2_b  = (const float*)d_in[23];
  const float* fin_g  = (const float*)d_in[24];
  const float* fin_b  = (const float*)d_in[25];

  float* ws    = (float*)d_ws;
  float* x0    = ws + O_X0;
  float* x1    = ws + O_X1;
  float* big   = ws + O_BIG;
  float* bsum  = ws + O_BSUM;
  unsigned long long* hpack = (unsigned long long*)(big + 8388608);

  u16*   aconv = (u16*)(ws + O_HSEQ);               // f16 activations [NT][512]
  float* qbias = ws + O_HSEQ + 2097152;             // 1536 scaled qkv bias
  u16*   qkvp  = (u16*)(ws + O_QKV);                // f16 qkv [NT][1536]
  u16*   ctxp  = (u16*)(ws + O_CTX);                // f16 ctx [NT][512]
  u16*   sc16  = (u16*)big;                         // f16 scores/P: spans ALL of big (64 MB)
  u32*   wsg   = (u32*)(big + 13000000);            // gates W packed scratch (pre-phase only)
  u16*   Wq    = (u16*)(big + 8388608);             // 786,432 u16 (layer start, dead hpack)
  u16*   Wo    = (u16*)(big + 8388608);             // 262,144 u16 (after pv)
  u16*   W1p   = (u16*)(big + 8650752);             // 1,048,576 u16
  u16*   W2p   = (u16*)(big + 9699328);             // 1,048,576 u16
  u16*   ffh   = (u16*)big;                         // f16 ffh [NT][2048] = [0..4.2M floats)

  float* outx  = (float*)d_out;            // [B,S,D]
  float* attn  = outx + (size_t)NT*DD;     // [L,B,S,S]

  hipMemsetAsync(hpack, 0, (size_t)(SS+1)*BB*DD*sizeof(unsigned long long), stream);

  const int eb = (NT*DD)/256;
  k_embed<<<eb, 256, 0, stream>>>(src, emb, x0);
  k_conv <<<eb, 256, 0, stream>>>(x0, conv_w, conv_b, bn_g, bn_b, bn_m, bn_v, x1, aconv);
  k_bsum <<<8, 256, 0, stream>>>(b_ih, b_hh, bsum, 4*DD);

  // LSTM input precompute: gates = x1 @ w_ih^T + (b_ih + b_hh)  (2-pass W for accuracy)
  k_wsplit<<<1024, 256, 0, stream>>>(w_ih, wsg, 2048*512);
  k_gemm2p<<<(NT/128)*((4*DD)/128), 256, 0, stream>>>(
      aconv, wsg, bsum, big, NT, 4*DD, DD);
  k_lstm<<<256, 256, 0, stream>>>(big, w_hh, hpack);
  k_resid<<<eb, 256, 0, stream>>>(x1, hpack, aconv);

  float* cur = x1;
  float* tmp = x0;
  for (int l=0; l<LL; ++l){
    // qkv weight split (consumed before scores clobber big)
    k_wsplit_qkv<<<768, 256, 0, stream>>>(in_w + (size_t)l*1536*DD,
                                          in_b + (size_t)l*1536, Wq, qbias);
    // qkv = cur @ in_w[l]^T + in_b[l]  (f16 out; BN=128, 384 blocks)
    k_gemmh<0,1><<<(NT/128)*(1536/128), 256, 0, stream>>>(
        aconv, Wq, qbias, qkvp, NT, 1536, DD);
    // attention, all 4 batches per dispatch
    k_scores_mfma<<<2048, 256, 0, stream>>>(qkvp, sc16);
    k_softmax    <<<4096, 256, 0, stream>>>(sc16, attn, l);
    k_pv_mfma    <<<512,  256, 0, stream>>>(sc16, qkvp, ctxp);
    // post-attention weight split (scores/P now dead)
    k_wsplit_post<<<2304, 256, 0, stream>>>(out_w + (size_t)l*DD*DD,
                                            w1 + (size_t)l*DFF*DD,
                                            w2 + (size_t)l*DD*DFF, Wo, W1p, W2p);
    // proj: tmp = ctx @ out_w[l]^T + out_b[l]
    k_gemm64h<0,0><<<(NT/128)*(DD/64), 256, 0, stream>>>(
        ctxp, Wo, out_b + (size_t)l*DD, tmp, NT, DD, DD);
    // ln1 -> cur (f32) + aconv (f16, consumed by ffn1)
    k_ln<<<NT, 64, 0, stream>>>(cur, tmp, ln1_g + l*DD, ln1_b + l*DD, cur, aconv);
    // ffh = gelu(cur @ w1[l]^T + b1[l])  -> f16 plane at big[0..4.2M floats)
    k_gemmh<1,1><<<(NT/128)*(DFF/128), 256, 0, stream>>>(
        aconv, W1p, b1 + (size_t)l*DFF, ffh, NT, DFF, DD);
    // tmp = ffh @ w2[l]^T + b2[l]
    k_gemm64h<0,0><<<(NT/128)*(DD/64), 256, 0, stream>>>(
        ffh, W2p, b2 + (size_t)l*DD, tmp, NT, DD, DFF);
    // ln2 -> cur (f32) + aconv (f16, consumed by next layer's qkv)
    k_ln<<<NT, 64, 0, stream>>>(cur, tmp, ln2_g + l*DD, ln2_b + l*DD, cur, aconv);
  }
  k_ln<<<NT, 64, 0, stream>>>(cur, nullptr, fin_g, fin_b, outx, nullptr);
}

// Round 16
// 2480.222 us; speedup vs baseline: 1.0557x; 1.0557x over previous
//
#include <hip/hip_runtime.h>
#include <math.h>

#define DD 512
#define SS 1024
#define BB 4
#define HH 8
#define DFF 2048
#define LL 4
#define NT 4096           // BB*SS
#define EPSF 1e-5f

// ---------------- workspace layout (float elements) ----------------
#define O_X0    ((size_t)0)            // 2,097,152  emb+pe / tmp
#define O_X1    ((size_t)2097152)      // 2,097,152  conv out / current x
#define O_HSEQ  ((size_t)4194304)      // 2,099,200: packed activation scratch (+qbias tail)
#define O_CTX   ((size_t)6293504)      // 2,097,152 (ctx, packed pairs)
#define O_QKV   ((size_t)8390656)      // 6,291,456 (packed split-pairs)
#define O_BIG   ((size_t)14682112)     // 16,777,216 (gates / f16 scores SPAN WHOLE REGION / ffh / W)
#define O_BSUM  ((size_t)31459328)     // 2048

typedef unsigned int  u32;
typedef unsigned short u16;
typedef __attribute__((ext_vector_type(8))) _Float16 f16x8;
typedef __attribute__((ext_vector_type(4))) _Float16 f16x4;
typedef __attribute__((ext_vector_type(4))) float    f32x4;

// fast transcendentals: v_exp_f32 / v_rcp_f32 based (~1e-7 rel, saturating-safe)
__device__ __forceinline__ float fsig(float x){
  return __builtin_amdgcn_rcpf(1.0f + __expf(-x));
}
__device__ __forceinline__ float ftanh(float x){
  return 1.0f - 2.0f*__builtin_amdgcn_rcpf(1.0f + __expf(2.0f*x));
}
union f16u { u16 u; _Float16 f; };
__device__ __forceinline__ float b2f(u16 b){ f16u t; t.u = b; return (float)t.f; }
__device__ __forceinline__ u16 f2b(_Float16 h){ f16u t; t.f = h; return t.u; }
// pack f32 -> {hi f16 (low16) | lo f16 (high16)}
__device__ __forceinline__ u32 pack2(float v){
  _Float16 hi = (_Float16)v;
  _Float16 lo = (_Float16)(v - (float)hi);
  return (u32)f2b(hi) | ((u32)f2b(lo) << 16);
}

// ---------------- embedding + sinusoidal PE ----------------
__global__ void k_embed(const int* __restrict__ src, const float* __restrict__ emb,
                        float* __restrict__ x){
  int idx = blockIdx.x*256 + threadIdx.x;
  if (idx >= NT*DD) return;
  int d = idx & (DD-1);
  int n = idx >> 9;          // b*SS + s
  int s = n & (SS-1);
  int tok = src[n];
  int i2 = d & ~1;
  float div = expf(-(float)i2 * (9.210340371976184f/512.0f));  // ln(10000)/512
  float ang = (float)s * div;
  float pe = (d & 1) ? cosf(ang) : sinf(ang);
  x[idx] = emb[(size_t)tok*DD + d]*22.62741699796952f + pe;    // sqrt(512)
}

// ---------------- depthwise conv k=3 + BN(eval) + ReLU (+ packed copy) ----------------
__global__ void k_conv(const float* __restrict__ x, const float* __restrict__ cw,
                       const float* __restrict__ cb, const float* __restrict__ bg,
                       const float* __restrict__ bb, const float* __restrict__ bm,
                       const float* __restrict__ bv, float* __restrict__ y,
                       u32* __restrict__ yp){
  int idx = blockIdx.x*256 + threadIdx.x;
  if (idx >= NT*DD) return;
  int d = idx & (DD-1);
  int n = idx >> 9;
  int s = n & (SS-1);
  float acc = cb[d];
  if (s > 0)     acc += x[idx - DD]*cw[d*3+0];
  acc += x[idx]*cw[d*3+1];
  if (s < SS-1)  acc += x[idx + DD]*cw[d*3+2];
  float v = (acc - bm[d])*rsqrtf(bv[d]+EPSF)*bg[d] + bb[d];
  v = fmaxf(v, 0.0f);
  y[idx] = v;
  yp[idx] = pack2(v);
}

__global__ void k_bsum(const float* a, const float* b, float* o, int n){
  int i = blockIdx.x*256 + threadIdx.x;
  if (i < n) o[i] = a[i] + b[i];
}

// ---------------- weight pre-split: W f32 -> packed {hi|lo} u32 ----------------
__global__ void k_wsplit(const float* __restrict__ W, u32* __restrict__ Wp, int total){
  int i = blockIdx.x*1024 + threadIdx.x*4;
  if (i >= total) return;
  float4 v = *reinterpret_cast<const float4*>(W + i);
  uint4 o;
  o.x = pack2(v.x); o.y = pack2(v.y); o.z = pack2(v.z); o.w = pack2(v.w);
  *reinterpret_cast<uint4*>(Wp + i) = o;
}

// qkv weight split (rows<512 scaled 0.125) + scaled bias. 786,432 u32 -> 768 blocks.
// MUST be consumed by the qkv GEMM before k_scores (scores clobber all of big).
__global__ void k_wsplit_qkv(const float* __restrict__ inw, const float* __restrict__ inb,
                             u32* __restrict__ Wq, float* __restrict__ qbias){
  size_t i = (size_t)blockIdx.x*1024 + threadIdx.x*4;
  float s = (i < 262144) ? 0.125f : 1.0f;
  float4 v = *reinterpret_cast<const float4*>(inw + i);
  uint4 o;
  o.x = pack2(v.x*s); o.y = pack2(v.y*s); o.z = pack2(v.z*s); o.w = pack2(v.w*s);
  *reinterpret_cast<uint4*>(Wq + i) = o;
  if (blockIdx.x == 0){
    for (int j = threadIdx.x; j < 1536; j += 256){
      float bv = inb[j];
      qbias[j] = (j < 512) ? bv*0.125f : bv;
    }
  }
}

// post-attention fused split: out_w 262,144 | w1 1,048,576 | w2 1,048,576 -> 2304 blocks.
// Launched AFTER k_pv (scores/P dead), scratches live over the dead score region.
__global__ void k_wsplit_post(const float* __restrict__ outw, const float* __restrict__ w1,
                              const float* __restrict__ w2,
                              u32* __restrict__ Wo, u32* __restrict__ W1p,
                              u32* __restrict__ W2p){
  size_t i = (size_t)blockIdx.x*1024 + threadIdx.x*4;
  const float* src; u32* dst; size_t off;
  if (i < 262144){ src = outw; dst = Wo; off = i; }
  else if (i < 1310720){ src = w1; dst = W1p; off = i - 262144; }
  else { src = w2; dst = W2p; off = i - 1310720; }
  float4 v = *reinterpret_cast<const float4*>(src + off);
  uint4 o;
  o.x = pack2(v.x); o.y = pack2(v.y); o.z = pack2(v.z); o.w = pack2(v.w);
  *reinterpret_cast<uint4*>(dst + off) = o;
}

// unpack helper for staging: 4 packed elems -> hi u32x2 + lo u32x2 (2 halves each)
__device__ __forceinline__ void unpk4(uint4 w, uint2& hi, uint2& lo){
  hi.x = (w.x & 0xffffu) | (w.y << 16);
  hi.y = (w.z & 0xffffu) | (w.w << 16);
  lo.x = (w.x >> 16) | (w.y & 0xffff0000u);
  lo.y = (w.z >> 16) | (w.w & 0xffff0000u);
}
__device__ __forceinline__ uint2 unpk4hi(uint4 w){
  uint2 hi;
  hi.x = (w.x & 0xffffu) | (w.y << 16);
  hi.y = (w.z & 0xffffu) | (w.w << 16);
  return hi;
}

// ---------------- MFMA split-f16 GEMM (128x128): C = A @ W^T + bias ----------------
// A and W pre-split packed pairs. 2-pass MFMA: C = Ah*Wh + Ah*Wl.
#define BKP 40   // padded K stride in halves
template<int ACT, int OSPLIT>
__global__ __launch_bounds__(256) void k_gemm_mfma(const u32* __restrict__ Ain,
                                                   const u32* __restrict__ Wp,
                                                   const float* __restrict__ bias,
                                                   void* __restrict__ Cout,
                                                   int M, int N, int K){
  __shared__ _Float16 Ah[128][BKP];
  __shared__ _Float16 Wh[128][BKP];
  __shared__ _Float16 Wl[128][BKP];
  const int tid = threadIdx.x;
  const int nbx = N >> 7;
  const int bx = blockIdx.x % nbx;
  const int by = blockIdx.x / nbx;
  const int m0 = by << 7, n0 = bx << 7;
  const int lane = tid & 63;
  const int wid  = tid >> 6;
  const int wr = wid >> 1, wc = wid & 1;
  const int fm = lane & 15, fg = lane >> 4;
  const int r0 = tid >> 3;              // staging row base (row = r0 + 32e)
  const int k4 = (tid & 7) << 2;        // staging k offset within tile
  const u32* Wbase = Wp + (size_t)(n0 + r0)*K + k4;
  const u32* Abase = Ain + (size_t)(m0 + r0)*K + k4;

  f32x4 acc[4][4];
  #pragma unroll
  for (int i=0;i<4;i++)
    #pragma unroll
    for (int j=0;j<4;j++) acc[i][j] = (f32x4){0.0f,0.0f,0.0f,0.0f};

  uint4 rw[4], ra4[4];
  #pragma unroll
  for (int e=0;e<4;e++){
    rw[e]  = *reinterpret_cast<const uint4*>(Wbase + (size_t)(e*32)*K);
    ra4[e] = *reinterpret_cast<const uint4*>(Abase + (size_t)(e*32)*K);
  }

  for (int k0 = 0; k0 < K; k0 += 32){
    #pragma unroll
    for (int e = 0; e < 4; ++e){
      int rr = r0 + e*32;
      uint2 hi, lo;
      unpk4(rw[e], hi, lo);
      *reinterpret_cast<uint2*>(&Wh[rr][k4]) = hi;
      *reinterpret_cast<uint2*>(&Wl[rr][k4]) = lo;
      *reinterpret_cast<uint2*>(&Ah[rr][k4]) = unpk4hi(ra4[e]);
    }
    __syncthreads();
    if (k0 + 32 < K){
      #pragma unroll
      for (int e=0;e<4;e++){
        rw[e]  = *reinterpret_cast<const uint4*>(Wbase + (size_t)(e*32)*K + k0 + 32);
        ra4[e] = *reinterpret_cast<const uint4*>(Abase + (size_t)(e*32)*K + k0 + 32);
      }
    }
    f16x8 a_h[4], w_h[4], w_l[4];
    #pragma unroll
    for (int i=0;i<4;i++){
      int row = wr*64 + i*16 + fm;
      a_h[i] = *reinterpret_cast<const f16x8*>(&Ah[row][fg*8]);
    }
    #pragma unroll
    for (int j=0;j<4;j++){
      int row = wc*64 + j*16 + fm;
      w_h[j] = *reinterpret_cast<const f16x8*>(&Wh[row][fg*8]);
      w_l[j] = *reinterpret_cast<const f16x8*>(&Wl[row][fg*8]);
    }
    #pragma unroll
    for (int i=0;i<4;i++)
      #pragma unroll
      for (int j=0;j<4;j++){
        acc[i][j] = __builtin_amdgcn_mfma_f32_16x16x32_f16(a_h[i], w_h[j], acc[i][j], 0, 0, 0);
        acc[i][j] = __builtin_amdgcn_mfma_f32_16x16x32_f16(a_h[i], w_l[j], acc[i][j], 0, 0, 0);
      }
    __syncthreads();
  }
  #pragma unroll
  for (int i=0;i<4;i++){
    #pragma unroll
    for (int r=0;r<4;r++){
      int row = m0 + wr*64 + i*16 + fg*4 + r;
      #pragma unroll
      for (int j=0;j<4;j++){
        int col = n0 + wc*64 + j*16 + fm;
        float v = acc[i][j][r] + bias[col];
        if (ACT == 1) v = 0.5f*v*(1.0f + erff(v*0.70710678118654752f));  // exact gelu
        if constexpr (OSPLIT) ((u32*)Cout)[(size_t)row*N + col] = pack2(v);
        else                  ((float*)Cout)[(size_t)row*N + col] = v;
      }
    }
  }
}

// ---------------- MFMA split-f16 GEMM (128x64) for N=512: full-chip grids ----------------
template<int ACT, int OSPLIT>
__global__ __launch_bounds__(256) void k_gemm64_mfma(const u32* __restrict__ Ain,
                                                     const u32* __restrict__ Wp,
                                                     const float* __restrict__ bias,
                                                     void* __restrict__ Cout,
                                                     int M, int N, int K){
  __shared__ _Float16 Ah[128][BKP];
  __shared__ _Float16 Wh[64][BKP];
  __shared__ _Float16 Wl[64][BKP];
  const int tid = threadIdx.x;
  const int nbx = N >> 6;
  const int bx = blockIdx.x % nbx;
  const int by = blockIdx.x / nbx;
  const int m0 = by << 7, n0 = bx << 6;
  const int lane = tid & 63;
  const int wid  = tid >> 6;
  const int wr = wid >> 1, wc = wid & 1;   // wave tile: 64 rows x 32 cols
  const int fm = lane & 15, fg = lane >> 4;
  const int r0 = tid >> 3;
  const int k4 = (tid & 7) << 2;
  const u32* Wbase = Wp + (size_t)(n0 + r0)*K + k4;   // rows r0 + 32e, e<2
  const u32* Abase = Ain + (size_t)(m0 + r0)*K + k4;  // rows r0 + 32e, e<4

  f32x4 acc[4][2];
  #pragma unroll
  for (int i=0;i<4;i++){ acc[i][0] = (f32x4){0,0,0,0}; acc[i][1] = (f32x4){0,0,0,0}; }

  uint4 rw[2], ra4[4];
  #pragma unroll
  for (int e=0;e<2;e++)
    rw[e]  = *reinterpret_cast<const uint4*>(Wbase + (size_t)(e*32)*K);
  #pragma unroll
  for (int e=0;e<4;e++)
    ra4[e] = *reinterpret_cast<const uint4*>(Abase + (size_t)(e*32)*K);

  for (int k0 = 0; k0 < K; k0 += 32){
    #pragma unroll
    for (int e = 0; e < 2; ++e){
      int rr = r0 + e*32;
      uint2 hi, lo;
      unpk4(rw[e], hi, lo);
      *reinterpret_cast<uint2*>(&Wh[rr][k4]) = hi;
      *reinterpret_cast<uint2*>(&Wl[rr][k4]) = lo;
    }
    #pragma unroll
    for (int e = 0; e < 4; ++e){
      int rr = r0 + e*32;
      *reinterpret_cast<uint2*>(&Ah[rr][k4]) = unpk4hi(ra4[e]);
    }
    __syncthreads();
    if (k0 + 32 < K){
      #pragma unroll
      for (int e=0;e<2;e++)
        rw[e]  = *reinterpret_cast<const uint4*>(Wbase + (size_t)(e*32)*K + k0 + 32);
      #pragma unroll
      for (int e=0;e<4;e++)
        ra4[e] = *reinterpret_cast<const uint4*>(Abase + (size_t)(e*32)*K + k0 + 32);
    }
    f16x8 a_h[4], w_h[2], w_l[2];
    #pragma unroll
    for (int i=0;i<4;i++){
      int row = wr*64 + i*16 + fm;
      a_h[i] = *reinterpret_cast<const f16x8*>(&Ah[row][fg*8]);
    }
    #pragma unroll
    for (int j=0;j<2;j++){
      int row = wc*32 + j*16 + fm;
      w_h[j] = *reinterpret_cast<const f16x8*>(&Wh[row][fg*8]);
      w_l[j] = *reinterpret_cast<const f16x8*>(&Wl[row][fg*8]);
    }
    #pragma unroll
    for (int i=0;i<4;i++)
      #pragma unroll
      for (int j=0;j<2;j++){
        acc[i][j] = __builtin_amdgcn_mfma_f32_16x16x32_f16(a_h[i], w_h[j], acc[i][j], 0, 0, 0);
        acc[i][j] = __builtin_amdgcn_mfma_f32_16x16x32_f16(a_h[i], w_l[j], acc[i][j], 0, 0, 0);
      }
    __syncthreads();
  }
  #pragma unroll
  for (int i=0;i<4;i++){
    #pragma unroll
    for (int r=0;r<4;r++){
      int row = m0 + wr*64 + i*16 + fg*4 + r;
      #pragma unroll
      for (int j=0;j<2;j++){
        int col = n0 + wc*32 + j*16 + fm;
        float v = acc[i][j][r] + bias[col];
        if (ACT == 1) v = 0.5f*v*(1.0f + erff(v*0.70710678118654752f));
        if constexpr (OSPLIT) ((u32*)Cout)[(size_t)row*N + col] = pack2(v);
        else                  ((float*)Cout)[(size_t)row*N + col] = v;
      }
    }
  }
}

// ---------------- MFMA attention scores: sc = Qs @ K^T (128x128 tiles) ----------------
// qkv packed pairs (Q pre-scaled 0.125). 2-pass: Qh*Kh + Qh*Kl.
// Output: f16 plane (u16/elem), all 4 batches in one dispatch (2048 blocks).
#define SPAD 72
__global__ __launch_bounds__(256) void k_scores_mfma(const u32* __restrict__ qkv,
                                                     u16* __restrict__ sc){
  __shared__ _Float16 Qh[128][SPAD];
  __shared__ _Float16 Kh[128][SPAD], Kl[128][SPAD];
  const int tid = threadIdx.x;
  const int kt = blockIdx.x & 7;
  const int qt = (blockIdx.x >> 3) & 7;
  const int h  = (blockIdx.x >> 6) & 7;
  const int b  = (blockIdx.x >> 9) & 3;
  const int q0 = qt*128, k0 = kt*128;
  #pragma unroll
  for (int e=0;e<8;e++){
    int lin = e*256 + tid;
    int rr = lin >> 4;
    int c4 = (lin & 15) << 2;
    uint4 qv = *reinterpret_cast<const uint4*>(qkv + (size_t)(b*SS + q0+rr)*1536 + h*64 + c4);
    uint4 kv = *reinterpret_cast<const uint4*>(qkv + (size_t)(b*SS + k0+rr)*1536 + DD + h*64 + c4);
    uint2 hi, lo;
    *reinterpret_cast<uint2*>(&Qh[rr][c4]) = unpk4hi(qv);
    unpk4(kv, hi, lo);
    *reinterpret_cast<uint2*>(&Kh[rr][c4]) = hi;
    *reinterpret_cast<uint2*>(&Kl[rr][c4]) = lo;
  }
  __syncthreads();
  const int lane = tid & 63, wid = tid >> 6;
  const int wr = wid >> 1, wc = wid & 1;
  const int fm = lane & 15, fg = lane >> 4;
  f32x4 acc[4][4];
  #pragma unroll
  for (int i=0;i<4;i++)
    #pragma unroll
    for (int j=0;j<4;j++) acc[i][j] = (f32x4){0.0f,0.0f,0.0f,0.0f};
  #pragma unroll
  for (int ks=0; ks<2; ks++){
    f16x8 ah[4], bh[4], bl[4];
    #pragma unroll
    for (int i=0;i<4;i++){
      int row = wr*64 + i*16 + fm;
      ah[i] = *reinterpret_cast<const f16x8*>(&Qh[row][ks*32 + fg*8]);
    }
    #pragma unroll
    for (int j=0;j<4;j++){
      int row = wc*64 + j*16 + fm;
      bh[j] = *reinterpret_cast<const f16x8*>(&Kh[row][ks*32 + fg*8]);
      bl[j] = *reinterpret_cast<const f16x8*>(&Kl[row][ks*32 + fg*8]);
    }
    #pragma unroll
    for (int i=0;i<4;i++)
      #pragma unroll
      for (int j=0;j<4;j++){
        acc[i][j] = __builtin_amdgcn_mfma_f32_16x16x32_f16(ah[i], bh[j], acc[i][j], 0, 0, 0);
        acc[i][j] = __builtin_amdgcn_mfma_f32_16x16x32_f16(ah[i], bl[j], acc[i][j], 0, 0, 0);
      }
  }
  u16* out = sc + (size_t)(b*HH + h)*SS*SS;
  #pragma unroll
  for (int i=0;i<4;i++){
    #pragma unroll
    for (int r=0;r<4;r++){
      int row = q0 + wr*64 + i*16 + fg*4 + r;
      #pragma unroll
      for (int j=0;j<4;j++){
        int col = k0 + wc*64 + j*16 + fm;
        out[(size_t)row*SS + col] = f2b((_Float16)acc[i][j][r]);
      }
    }
  }
}

// ---------------- MFMA PV: ctx[:, h*64..] = P @ V (64q x 64d tiles, BK=64) ----------------
// P f16 plane; V packed pairs; ctx written as packed pairs. All batches: 512 blocks.
__global__ __launch_bounds__(256) void k_pv_mfma(const u16* __restrict__ sc,
                                                 const u32* __restrict__ qkv,
                                                 u32* __restrict__ ctx){
  __shared__ _Float16 Ph[64][SPAD];
  __shared__ _Float16 Vh[64][SPAD],  Vl[64][SPAD];
  const int tid = threadIdx.x;
  const int qt = blockIdx.x & 15;
  const int h  = (blockIdx.x >> 4) & 7;
  const int b  = (blockIdx.x >> 7) & 3;
  const int q0 = qt*64;
  const u16* Pb = sc + (size_t)(b*HH + h)*SS*SS;
  const int lane = tid & 63, wid = tid >> 6;
  const int wr = wid >> 1, wc = wid & 1;      // wave tile: 32 rows x 32 cols
  const int fm = lane & 15, fg = lane >> 4;
  const int pr0 = tid >> 4;                   // P staging: rows pr0 + 16e (e<4)
  const int pc4 = (tid & 15) << 2;
  const int vd  = tid & 63;                   // V staging: dim
  const int vk0 = tid >> 6;                   // V staging: k = vk0 + 4e
  const u16* Pbase = Pb + (size_t)(q0 + pr0)*SS + pc4;
  const u32* Vbase = qkv + (size_t)(b*SS + vk0)*1536 + 1024 + h*64 + vd;
  f32x4 acc[2][2];
  #pragma unroll
  for (int i=0;i<2;i++){ acc[i][0] = (f32x4){0,0,0,0}; acc[i][1] = (f32x4){0,0,0,0}; }

  uint2 rp[4];
  u32   rv[16];
  #pragma unroll
  for (int e=0;e<4;e++)  rp[e] = *reinterpret_cast<const uint2*>(Pbase + (size_t)(e*16)*SS);
  #pragma unroll
  for (int e=0;e<16;e++) rv[e] = Vbase[(size_t)(e*4)*1536];

  for (int kk0=0; kk0<SS; kk0+=64){
    #pragma unroll
    for (int e=0;e<4;e++){
      int rr = pr0 + e*16;
      *reinterpret_cast<uint2*>(&Ph[rr][pc4]) = rp[e];   // f16 bits verbatim
    }
    #pragma unroll
    for (int e=0;e<16;e++){
      int k = vk0 + e*4;
      u32 w = rv[e];
      f16u thi, tlo; thi.u = (u16)w; tlo.u = (u16)(w >> 16);
      Vh[vd][k] = thi.f;
      Vl[vd][k] = tlo.f;
    }
    __syncthreads();
    if (kk0 + 64 < SS){
      #pragma unroll
      for (int e=0;e<4;e++)
        rp[e] = *reinterpret_cast<const uint2*>(Pbase + (size_t)(e*16)*SS + kk0 + 64);
      #pragma unroll
      for (int e=0;e<16;e++)
        rv[e] = Vbase[(size_t)(kk0 + 64 + e*4)*1536];
    }
    #pragma unroll
    for (int ks=0; ks<2; ks++){
      f16x8 ah[2], bh[2], bl[2];
      #pragma unroll
      for (int i=0;i<2;i++){
        int row = wr*32 + i*16 + fm;
        ah[i] = *reinterpret_cast<const f16x8*>(&Ph[row][ks*32 + fg*8]);
      }
      #pragma unroll
      for (int j=0;j<2;j++){
        int row = wc*32 + j*16 + fm;
        bh[j] = *reinterpret_cast<const f16x8*>(&Vh[row][ks*32 + fg*8]);
        bl[j] = *reinterpret_cast<const f16x8*>(&Vl[row][ks*32 + fg*8]);
      }
      #pragma unroll
      for (int i=0;i<2;i++)
        #pragma unroll
        for (int j=0;j<2;j++){
          acc[i][j] = __builtin_amdgcn_mfma_f32_16x16x32_f16(ah[i], bh[j], acc[i][j], 0, 0, 0);
          acc[i][j] = __builtin_amdgcn_mfma_f32_16x16x32_f16(ah[i], bl[j], acc[i][j], 0, 0, 0);
        }
    }
    __syncthreads();
  }
  #pragma unroll
  for (int i=0;i<2;i++){
    #pragma unroll
    for (int r=0;r<4;r++){
      int row = q0 + wr*32 + i*16 + fg*4 + r;
      #pragma unroll
      for (int j=0;j<2;j++){
        int col = wc*32 + j*16 + fm;
        ctx[(size_t)(b*SS + row)*DD + h*64 + col] = pack2(acc[i][j][r]);
      }
    }
  }
}

// ---------------- persistent LSTM: FROZEN (R9-verified) ----------------
__global__ __launch_bounds__(256) void k_lstm(const float* __restrict__ gates_in,
                                              const float* __restrict__ w_hh,
                                              unsigned long long* __restrict__ hpack){
  __shared__ float hsh[2][8][68];
  const int b = blockIdx.x >> 6;
  const int chunk = blockIdx.x & 63;
  const int d0 = chunk*8;
  const int tid = threadIdx.x;
  const int wave = tid >> 6;
  const int lane = tid & 63;
  const int diw = lane >> 5;
  const int g   = (lane >> 3) & 3;
  const int ks  = lane & 7;
  const int dim = wave*2 + diw;
  const int src0 = diw*32;
  float w[64];
  {
    const float* wrow = w_hh + (size_t)(g*DD + d0 + dim)*DD;
    #pragma unroll
    for (int j=0;j<64;j++) w[j] = wrow[j*8 + ks];
  }
  float c = 0.0f;
  const float* gbase = gates_in + (size_t)(b*SS)*(4*DD) + g*DD + d0 + dim;
  unsigned long long p0 = __hip_atomic_load(hpack + (size_t)b*DD + tid,
                                            __ATOMIC_RELAXED, __HIP_MEMORY_SCOPE_AGENT);
  unsigned long long p1 = __hip_atomic_load(hpack + (size_t)b*DD + tid + 256,
                                            __ATOMIC_RELAXED, __HIP_MEMORY_SCOPE_AGENT);
  for (int t=0; t<SS; ++t){
    float gv = 0.0f;
    if (ks == 0) gv = gbase[(size_t)t*(4*DD)];
    const unsigned long long exp_tag = (unsigned long long)t;
    unsigned long long* hp = hpack + (size_t)(t*BB + b)*DD;
    while ((p0 >> 32) != exp_tag || (p1 >> 32) != exp_tag){
      if ((p0 >> 32) != exp_tag)
        p0 = __hip_atomic_load(hp + tid,       __ATOMIC_RELAXED, __HIP_MEMORY_SCOPE_AGENT);
      if ((p1 >> 32) != exp_tag)
        p1 = __hip_atomic_load(hp + tid + 256, __ATOMIC_RELAXED, __HIP_MEMORY_SCOPE_AGENT);
    }
    float (*hs)[68] = hsh[t & 1];
    union { unsigned int u; float f; } u0, u1;
    u0.u = (unsigned int)p0;
    u1.u = (unsigned int)p1;
    hs[tid & 7][tid >> 3]        = u0.f;
    hs[tid & 7][(tid >> 3) + 32] = u1.f;
    __syncthreads();
    if (t + 1 < SS){
      unsigned long long* hq = hpack + (size_t)((t+1)*BB + b)*DD;
      p0 = __hip_atomic_load(hq + tid,       __ATOMIC_RELAXED, __HIP_MEMORY_SCOPE_AGENT);
      p1 = __hip_atomic_load(hq + tid + 256, __ATOMIC_RELAXED, __HIP_MEMORY_SCOPE_AGENT);
    }
    float a0=0.0f, a1=0.0f, a2=0.0f, a3=0.0f;
    #pragma unroll
    for (int j=0;j<64;j+=4){
      float4 hv = *reinterpret_cast<const float4*>(&hs[ks][j]);
      a0 += w[j+0]*hv.x;
      a1 += w[j+1]*hv.y;
      a2 += w[j+2]*hv.z;
      a3 += w[j+3]*hv.w;
    }
    float acc = (a0+a1)+(a2+a3);
    acc += __shfl_down(acc, 4, 8);
    acc += __shfl_down(acc, 2, 8);
    acc += __shfl_down(acc, 1, 8);
    float v = acc + gv;
    float gval = (g == 2) ? ftanh(v) : fsig(v);
    float gi = __shfl(gval, src0 + 0);
    float gf = __shfl(gval, src0 + 8);
    float gg = __shfl(gval, src0 + 16);
    float go = __shfl(gval, src0 + 24);
    c = gf*c + gi*gg;
    float h = go*ftanh(c);
    if (lane == src0){
      union { float f; unsigned int u; } hu; hu.f = h;
      unsigned long long pk = ((unsigned long long)(unsigned int)(t+1) << 32)
                            | (unsigned long long)hu.u;
      __hip_atomic_store(&hpack[(size_t)((t+1)*BB + b)*DD + d0 + dim], pk,
                         __ATOMIC_RELAXED, __HIP_MEMORY_SCOPE_AGENT);
    }
  }
}

__global__ void k_resid(float* __restrict__ x, const unsigned long long* __restrict__ hpack,
                        u32* __restrict__ xp){
  int idx = blockIdx.x*256 + threadIdx.x;
  if (idx >= NT*DD) return;
  int d = idx & (DD-1);
  int n = idx >> 9;
  int s = n & (SS-1);
  int b = n >> 10;
  union { unsigned int u; float f; } hu;
  hu.u = (unsigned int)hpack[(size_t)((s+1)*BB + b)*DD + d];
  float v = x[idx] + hu.f;
  x[idx] = v;
  xp[idx] = pack2(v);
}

// softmax: reads f16 scores, writes P f16 in-place + head-average to d_out.
// All 4 batches: 4096 blocks. 4 waves x 2 heads, 1 barrier.
__global__ __launch_bounds__(256) void k_softmax(u16* __restrict__ sc,
                                                 float* __restrict__ attn_out,
                                                 int l){
  __shared__ float avgw[4][SS];
  const int tid = threadIdx.x;
  const int q  = blockIdx.x & (SS-1);
  const int b  = blockIdx.x >> 10;
  const int wave = tid >> 6, lane = tid & 63;
  #pragma unroll
  for (int j=0;j<16;j++) avgw[wave][j*64 + lane] = 0.0f;
  #pragma unroll
  for (int hi=0; hi<2; hi++){
    int h = wave + hi*4;
    u16* row = sc + (size_t)(b*HH + h)*SS*SS + (size_t)q*SS;
    float v[16];
    float m = -1e30f;
    #pragma unroll
    for (int j=0;j<16;j++){ v[j] = b2f(row[j*64 + lane]); m = fmaxf(m, v[j]); }
    #pragma unroll
    for (int o=32;o>0;o>>=1) m = fmaxf(m, __shfl_xor(m, o));
    float s = 0.0f;
    #pragma unroll
    for (int j=0;j<16;j++){ v[j] = __expf(v[j] - m); s += v[j]; }
    #pragma unroll
    for (int o=32;o>0;o>>=1) s += __shfl_xor(s, o);
    float inv = __builtin_amdgcn_rcpf(s);
    #pragma unroll
    for (int j=0;j<16;j++){
      float p = v[j]*inv;
      row[j*64 + lane] = f2b((_Float16)p);
      avgw[wave][j*64 + lane] += p;
    }
  }
  __syncthreads();
  float* ao = attn_out + (size_t)((l*BB + b)*SS + q)*SS;
  for (int j=tid;j<SS;j+=256)
    ao[j] = (avgw[0][j]+avgw[1][j]+avgw[2][j]+avgw[3][j])*0.125f;
}

// ---------------- LayerNorm: out = LN(x (+ y)) * g + b  (+ optional packed copy) ----------------
__global__ __launch_bounds__(64) void k_ln(const float* __restrict__ x,
                                           const float* __restrict__ y,
                                           const float* __restrict__ g,
                                           const float* __restrict__ bta,
                                           float* __restrict__ out,
                                           u32* __restrict__ outp){
  const int n = blockIdx.x;
  const int tid = threadIdx.x;
  float v[8];
  float s = 0.0f, sq = 0.0f;
  #pragma unroll
  for (int j=0;j<8;j++){
    int d = j*64 + tid;
    float a = x[(size_t)n*DD + d];
    if (y) a += y[(size_t)n*DD + d];
    v[j] = a; s += a; sq += a*a;
  }
  #pragma unroll
  for (int o=32;o>0;o>>=1){ s += __shfl_xor(s, o); sq += __shfl_xor(sq, o); }
  float mean = s*(1.0f/DD);
  float var = sq*(1.0f/DD) - mean*mean;
  float rstd = rsqrtf(var + EPSF);
  #pragma unroll
  for (int j=0;j<8;j++){
    int d = j*64 + tid;
    float r = (v[j]-mean)*rstd*g[d] + bta[d];
    out[(size_t)n*DD + d] = r;
    if (outp) outp[(size_t)n*DD + d] = pack2(r);
  }
}

extern "C" void kernel_launch(void* const* d_in, const int* in_sizes, int n_in,
                              void* d_out, int out_size, void* d_ws, size_t ws_size,
                              hipStream_t stream){
  const int*   src    = (const int*)  d_in[0];
  const float* emb    = (const float*)d_in[1];
  const float* conv_w = (const float*)d_in[2];
  const float* conv_b = (const float*)d_in[3];
  const float* bn_g   = (const float*)d_in[4];
  const float* bn_b   = (const float*)d_in[5];
  const float* bn_m   = (const float*)d_in[6];
  const float* bn_v   = (const float*)d_in[7];
  const float* w_ih   = (const float*)d_in[8];
  const float* w_hh   = (const float*)d_in[9];
  const float* b_ih   = (const float*)d_in[10];
  const float* b_hh   = (const float*)d_in[11];
  const float* in_w   = (const float*)d_in[12];
  const float* in_b   = (const float*)d_in[13];
  const float* out_w  = (const float*)d_in[14];
  const float* out_b  = (const float*)d_in[15];
  const float* ln1_g  = (const float*)d_in[16];
  const float* ln1_b  = (const float*)d_in[17];
  const float* w1     = (const float*)d_in[18];
  const float* b1     = (const float*)d_in[19];
  const float* w2     = (const float*)d_in[20];
  const float* b2     = (const float*)d_in[21];
  const float* ln2_g  = (const float*)d_in[22];
  const float* ln2_b  = (const float*)d_in[23];
  const float* fin_g  = (const float*)d_in[24];
  const float* fin_b  = (const float*)d_in[25];

  float* ws    = (float*)d_ws;
  float* x0    = ws + O_X0;
  float* x1    = ws + O_X1;
  float* ctx   = ws + O_CTX;
  float* qkv   = ws + O_QKV;
  float* big   = ws + O_BIG;
  float* bsum  = ws + O_BSUM;
  unsigned long long* hpack = (unsigned long long*)(big + 8388608);

  u32*   aconv = (u32*)(ws + O_HSEQ);               // 2,097,152 packed activations
  float* qbias = ws + O_HSEQ + 2097152;             // 1536 scaled qkv bias
  u32*   qkvp  = (u32*)qkv;
  u32*   ctxp  = (u32*)ctx;
  u16*   sc16  = (u16*)big;                         // f16 scores/P: spans ALL of big (64 MB)
  u32*   wsg   = (u32*)(big + 13000000);            // gates W scratch (pre-phase only)
  // Wq: written at layer start (dead hpack region), consumed by qkv GEMM BEFORE scores.
  u32*   Wq    = (u32*)(big + 8388608);             // 786,432
  // Wo/W1p/W2p: written AFTER pv (scores dead), in big[8.39M..10.75M); ffh uses [0..8.39M).
  u32*   Wo    = (u32*)(big + 8388608);             // 262,144
  u32*   W1p   = (u32*)(big + 8650752);             // 1,048,576
  u32*   W2p   = (u32*)(big + 9699328);             // 1,048,576 (ends 10,747,904)

  float* outx  = (float*)d_out;            // [B,S,D]
  float* attn  = outx + (size_t)NT*DD;     // [L,B,S,S]

  hipMemsetAsync(hpack, 0, (size_t)(SS+1)*BB*DD*sizeof(unsigned long long), stream);

  const int eb = (NT*DD)/256;
  k_embed<<<eb, 256, 0, stream>>>(src, emb, x0);
  k_conv <<<eb, 256, 0, stream>>>(x0, conv_w, conv_b, bn_g, bn_b, bn_m, bn_v, x1, aconv);
  k_bsum <<<8, 256, 0, stream>>>(b_ih, b_hh, bsum, 4*DD);

  // LSTM input precompute: gates = x1 @ w_ih^T + (b_ih + b_hh)
  k_wsplit<<<1024, 256, 0, stream>>>(w_ih, wsg, 2048*512);
  k_gemm_mfma<0,0><<<(NT/128)*((4*DD)/128), 256, 0, stream>>>(
      aconv, wsg, bsum, big, NT, 4*DD, DD);
  k_lstm<<<256, 256, 0, stream>>>(big, w_hh, hpack);
  k_resid<<<eb, 256, 0, stream>>>(x1, hpack, aconv);

  float* cur = x1;
  float* tmp = x0;
  for (int l=0; l<LL; ++l){
    // qkv weight split (consumed before scores clobber big)
    k_wsplit_qkv<<<768, 256, 0, stream>>>(in_w + (size_t)l*1536*DD,
                                          in_b + (size_t)l*1536, Wq, qbias);
    // qkv = cur @ in_w[l]^T + in_b[l]  (packed output)
    k_gemm_mfma<0,1><<<(NT/128)*(1536/128), 256, 0, stream>>>(
        aconv, Wq, qbias, qkvp, NT, 1536, DD);
    // attention, all 4 batches per dispatch (scores span the whole big region)
    k_scores_mfma<<<2048, 256, 0, stream>>>(qkvp, sc16);
    k_softmax    <<<4096, 256, 0, stream>>>(sc16, attn, l);
    k_pv_mfma    <<<512,  256, 0, stream>>>(sc16, qkvp, ctxp);
    // post-attention weight split (scores/P now dead)
    k_wsplit_post<<<2304, 256, 0, stream>>>(out_w + (size_t)l*DD*DD,
                                            w1 + (size_t)l*DFF*DD,
                                            w2 + (size_t)l*DD*DFF, Wo, W1p, W2p);
    // proj: tmp = ctx @ out_w[l]^T + out_b[l]  (full-chip 128x64 tiles)
    k_gemm64_mfma<0,0><<<(NT/128)*(DD/64), 256, 0, stream>>>(
        ctxp, Wo, out_b + (size_t)l*DD, tmp, NT, DD, DD);
    // ln1 -> cur (f32) + aconv (packed, consumed by ffn1)
    k_ln<<<NT, 64, 0, stream>>>(cur, tmp, ln1_g + l*DD, ln1_b + l*DD, cur, aconv);
    // ffh = gelu(cur @ w1[l]^T + b1[l])  -> packed pairs in big[0..8.39M)
    k_gemm_mfma<1,1><<<(NT/128)*(DFF/128), 256, 0, stream>>>(
        aconv, W1p, b1 + (size_t)l*DFF, (u32*)big, NT, DFF, DD);
    // tmp = ffh @ w2[l]^T + b2[l]  (full-chip 128x64 tiles)
    k_gemm64_mfma<0,0><<<(NT/128)*(DD/64), 256, 0, stream>>>(
        (u32*)big, W2p, b2 + (size_t)l*DD, tmp, NT, DD, DFF);
    // ln2 -> cur (f32) + aconv (packed, consumed by next layer's qkv)
    k_ln<<<NT, 64, 0, stream>>>(cur, tmp, ln2_g + l*DD, ln2_b + l*DD, cur, aconv);
  }
  k_ln<<<NT, 64, 0, stream>>>(cur, nullptr, fin_g, fin_b, outx, nullptr);
}